// Round 4
// baseline (539.659 us; speedup 1.0000x reference)
//
#include <hip/hip_runtime.h>
#include <hip/hip_bf16.h>

#define N_NODES 50000
#define N_EDGES 800000
#define DD 64
#define RPB 64
#define GBLOCKS ((N_NODES + RPB - 1) / RPB)   // 782
#define BN_EPS 1e-5f

// ws layout (floats), total 2 KB + 12.8 MB:
//   [0..127]   sums  : S1[64], S2[64]  (atomic BN stats; zeroed by sniff, re-zeroed by bn_params)
//   [128..255] scsh  : scale[64], shift[64]
//   [256..]    flags : int isf, int i64
//   [512..]    bufA  : 3.2M fp32  (agg1 -> hpre1 ; agg2 -> hpre2)
// h1 fp32 lives in d_out[0:N*D) and doubles as the layer-2 gather source.

__device__ __forceinline__ float bf2f(unsigned short b) {
    return __uint_as_float(((unsigned)b) << 16);
}
__device__ __forceinline__ float loadF(const void* p, int i, int isf) {
    return isf ? ((const float*)p)[i] : bf2f(((const unsigned short*)p)[i]);
}

// Detect wire formats; zero the BN sums. flags[0]=1 iff floats fp32; flags[1]=1 iff ints int64.
__global__ void sniff_kernel(const void* __restrict__ x, const int* __restrict__ ei,
                             int* __restrict__ flags, float* __restrict__ sums) {
    __shared__ int cntF, cntI;
    int t = threadIdx.x;
    if (t == 0) { cntF = 0; cntI = 0; }
    __syncthreads();
    if (t < 128) sums[t] = 0.0f;
    // even 16-bit words: bf16 value (exp in [0x70,0x8F] ~always for N(0,1)) vs
    // fp32 low-mantissa half (uniform -> ~12.5% pass)
    unsigned short w = ((const unsigned short*)x)[2 * t];
    int e = (w >> 7) & 0xFF;
    if (e >= 0x70 && e <= 0x8F) atomicAdd(&cntF, 1);
    // odd 32-bit words: ~all zero iff int64 (ids < 2^31); random iff int32
    if (t < 128 && ei[2 * t + 1] == 0) atomicAdd(&cntI, 1);
    __syncthreads();
    if (t == 0) {
        flags[0] = (cntF < 128) ? 1 : 0;
        flags[1] = (cntI > 64) ? 1 : 0;
    }
}

// agg[i] = (float)x[i]   (fuses the "+ x" of h = agg + x)
__global__ void init_cast_kernel(const void* __restrict__ x, float* __restrict__ agg,
                                 const int* __restrict__ flags) {
    int isf = flags[0];
    int i = (blockIdx.x * 256 + threadIdx.x) * 4;
    float4 f;
    if (isf) {
        f = *reinterpret_cast<const float4*>((const float*)x + i);
    } else {
        ushort4 u = *reinterpret_cast<const ushort4*>((const unsigned short*)x + i);
        f = make_float4(bf2f(u.x), bf2f(u.y), bf2f(u.z), bf2f(u.w));
    }
    *reinterpret_cast<float4*>(agg + i) = f;
}

// 64 lanes per edge: agg[dst][lane] += x[src][lane]  (x in input wire format)
__global__ void scatter1_kernel(const int* __restrict__ ei, const void* __restrict__ x,
                                float* agg, const int* __restrict__ flags) {
    int isf = flags[0], i64 = flags[1];
    int t = blockIdx.x * 256 + threadIdx.x;
    int e = t >> 6, lane = t & 63;
    int s, d;
    if (i64) { s = ei[2 * e]; d = ei[2 * N_EDGES + 2 * e]; }
    else     { s = ei[e];     d = ei[N_EDGES + e]; }
    atomicAdd(agg + d * DD + lane, loadF(x, s * DD + lane, isf));
}

// layer-2: gather h1 fp32 (from d_out)
__global__ void scatter2_kernel(const int* __restrict__ ei, const float* __restrict__ h,
                                float* agg, const int* __restrict__ flags) {
    int i64 = flags[1];
    int t = blockIdx.x * 256 + threadIdx.x;
    int e = t >> 6, lane = t & 63;
    int s, d;
    if (i64) { s = ei[2 * e]; d = ei[2 * N_EDGES + 2 * e]; }
    else     { s = ei[e];     d = ei[N_EDGES + e]; }
    atomicAdd(agg + d * DD + lane, h[s * DD + lane]);
}

// out = in @ W + b  (in fp32 [N,64]; W/b wire format); BN sums via 128 global atomics.
// Safe in-place (out_ == in_): block rows staged to LDS before any write.
__global__ __launch_bounds__(256) void gemm_stats_kernel(
    const float* in_, const void* __restrict__ W, const void* __restrict__ bias,
    float* out_, float* __restrict__ sums, const int* __restrict__ flags)
{
    __shared__ float sIn[RPB][DD];
    __shared__ float r1[4][DD];
    __shared__ float r2[4][DD];
    int isf = flags[0];
    int tid = threadIdx.x;
    int c = tid & 63, g = tid >> 6;
    int row0 = blockIdx.x * RPB;

    float wcol[DD];
    #pragma unroll
    for (int k = 0; k < DD; ++k) wcol[k] = loadF(W, k * DD + c, isf);
    float bv = loadF(bias, c, isf);

    #pragma unroll
    for (int j = 0; j < 4; ++j) {
        int lr = (tid >> 4) + 16 * j;
        int cc = (tid & 15) << 2;
        int r = row0 + lr;
        float4 v = make_float4(0.f, 0.f, 0.f, 0.f);
        if (r < N_NODES) v = *reinterpret_cast<const float4*>(in_ + r * DD + cc);
        *reinterpret_cast<float4*>(&sIn[lr][cc]) = v;
    }
    __syncthreads();

    float s1 = 0.f, s2 = 0.f;
    #pragma unroll 4
    for (int j = 0; j < 16; ++j) {
        int lr = g * 16 + j;
        float a0 = 0.f, a1 = 0.f, a2 = 0.f, a3 = 0.f;
        #pragma unroll
        for (int k = 0; k < DD; k += 4) {
            float4 a = *reinterpret_cast<const float4*>(&sIn[lr][k]);  // wave-uniform broadcast
            a0 += a.x * wcol[k];
            a1 += a.y * wcol[k + 1];
            a2 += a.z * wcol[k + 2];
            a3 += a.w * wcol[k + 3];
        }
        float acc = bv + ((a0 + a1) + (a2 + a3));
        int r = row0 + lr;
        if (r < N_NODES) {
            out_[r * DD + c] = acc;
            s1 += acc;
            s2 += acc * acc;
        }
    }
    r1[g][c] = s1; r2[g][c] = s2;
    __syncthreads();
    if (g == 0) {
        atomicAdd(&sums[c],      r1[0][c] + r1[1][c] + r1[2][c] + r1[3][c]);
        atomicAdd(&sums[64 + c], r2[0][c] + r2[1][c] + r2[2][c] + r2[3][c]);
    }
}

// sums -> scale/shift (BN affine folded): h_bn = h*scale + shift. Re-zeroes sums.
__global__ void bn_params_kernel(float* __restrict__ sums,
                                 const void* __restrict__ gma, const void* __restrict__ beta,
                                 float* __restrict__ scsh, const int* __restrict__ flags)
{
    int isf = flags[0];
    int c = threadIdx.x;   // 64 threads
    float S1 = sums[c];
    float S2 = sums[64 + c];
    float mean = S1 * (1.0f / N_NODES);
    float var  = S2 * (1.0f / N_NODES) - mean * mean;
    float scale = rsqrtf(var + BN_EPS) * loadF(gma, c, isf);
    scsh[c] = scale;
    scsh[DD + c] = loadF(beta, c, isf) - mean * scale;
    sums[c] = 0.0f;
    sums[64 + c] = 0.0f;
}

// h = relu(hpre*scale+shift); out = relu(h @ W2 + b2) -> fp32 oF (+ optional fp32 ofA).
// Safe with ofA == in_ (staged reads).
__global__ __launch_bounds__(256) void mlp2_kernel(
    const float* in_, const float* __restrict__ scsh,
    const void* __restrict__ W, const void* __restrict__ bias,
    float* __restrict__ oF, float* ofA, const int* __restrict__ flags)
{
    __shared__ float sIn[RPB][DD];
    int isf = flags[0];
    int tid = threadIdx.x;
    int c = tid & 63, g = tid >> 6;
    int row0 = blockIdx.x * RPB;

    float wcol[DD];
    #pragma unroll
    for (int k = 0; k < DD; ++k) wcol[k] = loadF(W, k * DD + c, isf);
    float bv = loadF(bias, c, isf);

    #pragma unroll
    for (int j = 0; j < 4; ++j) {
        int lr = (tid >> 4) + 16 * j;
        int cc = (tid & 15) << 2;
        int r = row0 + lr;
        float4 v = make_float4(0.f, 0.f, 0.f, 0.f);
        if (r < N_NODES) {
            v = *reinterpret_cast<const float4*>(in_ + r * DD + cc);
            float4 sc = *reinterpret_cast<const float4*>(scsh + cc);
            float4 sh = *reinterpret_cast<const float4*>(scsh + DD + cc);
            v.x = fmaxf(v.x * sc.x + sh.x, 0.f);
            v.y = fmaxf(v.y * sc.y + sh.y, 0.f);
            v.z = fmaxf(v.z * sc.z + sh.z, 0.f);
            v.w = fmaxf(v.w * sc.w + sh.w, 0.f);
        }
        *reinterpret_cast<float4*>(&sIn[lr][cc]) = v;
    }
    __syncthreads();

    #pragma unroll 4
    for (int j = 0; j < 16; ++j) {
        int lr = g * 16 + j;
        float a0 = 0.f, a1 = 0.f, a2 = 0.f, a3 = 0.f;
        #pragma unroll
        for (int k = 0; k < DD; k += 4) {
            float4 a = *reinterpret_cast<const float4*>(&sIn[lr][k]);
            a0 += a.x * wcol[k];
            a1 += a.y * wcol[k + 1];
            a2 += a.z * wcol[k + 2];
            a3 += a.w * wcol[k + 3];
        }
        float acc = fmaxf(bv + ((a0 + a1) + (a2 + a3)), 0.f);
        int r = row0 + lr;
        if (r < N_NODES) {
            oF[r * DD + c] = acc;            // fp32 output
            if (ofA) ofA[r * DD + c] = acc;  // fp32 copy for agg2 self-term
        }
    }
}

extern "C" void kernel_launch(void* const* d_in, const int* in_sizes, int n_in,
                              void* d_out, int out_size, void* d_ws, size_t ws_size,
                              hipStream_t stream)
{
    (void)in_sizes; (void)n_in; (void)out_size; (void)ws_size;
    const void* x  = d_in[0];
    const int* ei  = (const int*)d_in[1];
    const void* W1_0 = d_in[2];  const void* b1_0 = d_in[3];
    const void* g_0  = d_in[4];  const void* be_0 = d_in[5];
    const void* W2_0 = d_in[6];  const void* b2_0 = d_in[7];
    const void* W1_1 = d_in[8];  const void* b1_1 = d_in[9];
    const void* g_1  = d_in[10]; const void* be_1 = d_in[11];
    const void* W2_1 = d_in[12]; const void* b2_1 = d_in[13];

    float* wsf  = (float*)d_ws;
    float* sums = wsf;                 // 128
    float* scsh = wsf + 128;           // 128
    int*  flags = (int*)(wsf + 256);   // 2
    float* bufA = wsf + 512;           // 3.2M fp32
    float* out  = (float*)d_out;       // fp32! h1 = out[0:N*D), h2 = out[N*D:2*N*D)

    dim3 blk(256);

    sniff_kernel<<<1, blk, 0, stream>>>(x, ei, flags, sums);

    // ---- layer 1 ----
    init_cast_kernel<<<N_NODES * DD / 1024, blk, 0, stream>>>(x, bufA, flags);
    scatter1_kernel<<<N_EDGES * 64 / 256, blk, 0, stream>>>(ei, x, bufA, flags);
    gemm_stats_kernel<<<GBLOCKS, blk, 0, stream>>>(bufA, W1_0, b1_0, bufA, sums, flags);
    bn_params_kernel<<<1, 64, 0, stream>>>(sums, g_0, be_0, scsh, flags);
    // h1 fp32 -> out[0:N*D)  (also the layer-2 gather source) ; fp32 -> bufA (agg2 self-term)
    mlp2_kernel<<<GBLOCKS, blk, 0, stream>>>(bufA, scsh, W2_0, b2_0, out, bufA, flags);

    // ---- layer 2 ----
    scatter2_kernel<<<N_EDGES * 64 / 256, blk, 0, stream>>>(ei, out, bufA, flags);
    gemm_stats_kernel<<<GBLOCKS, blk, 0, stream>>>(bufA, W1_1, b1_1, bufA, sums, flags);
    bn_params_kernel<<<1, 64, 0, stream>>>(sums, g_1, be_1, scsh, flags);
    mlp2_kernel<<<GBLOCKS, blk, 0, stream>>>(bufA, scsh, W2_1, b2_1,
                                             out + (size_t)N_NODES * DD, nullptr, flags);
}

// Round 5
// 483.700 us; speedup vs baseline: 1.1157x; 1.1157x over previous
//
#include <hip/hip_runtime.h>
#include <hip/hip_bf16.h>

#define N_NODES 50000
#define N_EDGES 800000
#define DD 64
#define RPB 64
#define GBLOCKS ((N_NODES + RPB - 1) / RPB)   // 782
#define BN_EPS 1e-5f

// ws layout (fp32 words), ~3.8 MB total:
//   [0..127]    sums (atomic BN stats)      [128..255] scsh (scale/shift)
//   [256..]     flags (int isf, int i64)
//   [512..]     cnt[50000], off[50001], cur[50000], srt[800000]
// d_out (fp32): O1 = h1 (also layer-2 gather source), O2 = scratch hpre -> h2.

__device__ __forceinline__ float bf2f(unsigned short b) {
    return __uint_as_float(((unsigned)b) << 16);
}
__device__ __forceinline__ float loadF(const void* p, int i, int isf) {
    return isf ? ((const float*)p)[i] : bf2f(((const unsigned short*)p)[i]);
}
template<bool ISF>
__device__ __forceinline__ float ld(const void* p, int i) {
    return ISF ? ((const float*)p)[i] : bf2f(((const unsigned short*)p)[i]);
}

// zero CSR counts + BN sums
__global__ void zero_kernel(int* __restrict__ cnt, float* __restrict__ sums) {
    int i = blockIdx.x * 256 + threadIdx.x;
    if (i < N_NODES) cnt[i] = 0;
    if (i < 128) sums[i] = 0.0f;
}

// Detect wire formats. flags[0]=1 iff floats fp32; flags[1]=1 iff ints int64.
__global__ void sniff_kernel(const void* __restrict__ x, const int* __restrict__ ei,
                             int* __restrict__ flags) {
    __shared__ int cntF, cntI;
    int t = threadIdx.x;
    if (t == 0) { cntF = 0; cntI = 0; }
    __syncthreads();
    unsigned short w = ((const unsigned short*)x)[2 * t];
    int e = (w >> 7) & 0xFF;
    if (e >= 0x70 && e <= 0x8F) atomicAdd(&cntF, 1);      // bf16-plausible exponent
    if (t < 128 && ei[2 * t + 1] == 0) atomicAdd(&cntI, 1); // int64 high words are 0
    __syncthreads();
    if (t == 0) {
        flags[0] = (cntF < 128) ? 1 : 0;
        flags[1] = (cntI > 64) ? 1 : 0;
    }
}

__global__ void hist_kernel(const int* __restrict__ ei, int* __restrict__ cnt,
                            const int* __restrict__ flags) {
    int i64 = flags[1];
    int e = blockIdx.x * 256 + threadIdx.x;
    int d = i64 ? ei[2 * N_EDGES + 2 * e] : ei[N_EDGES + e];
    atomicAdd(cnt + d, 1);
}

// single-block exclusive scan of cnt[50000] -> off[50001]; cur := off
#define CHUNK 49  // 1024*49 >= 50000
__global__ __launch_bounds__(1024) void scan_kernel(const int* __restrict__ cnt,
                                                    int* __restrict__ off,
                                                    int* __restrict__ cur) {
    __shared__ int part[1024];
    int t = threadIdx.x;
    int lo = t * CHUNK;
    int hi = min(lo + CHUNK, N_NODES);
    int s = 0;
    for (int i = lo; i < hi; ++i) s += cnt[i];
    part[t] = s;
    __syncthreads();
    for (int d = 1; d < 1024; d <<= 1) {     // Hillis-Steele inclusive
        int v = (t >= d) ? part[t - d] : 0;
        __syncthreads();
        part[t] += v;
        __syncthreads();
    }
    int run = (t == 0) ? 0 : part[t - 1];    // exclusive base
    for (int i = lo; i < hi; ++i) {
        off[i] = run; cur[i] = run;
        run += cnt[i];
    }
    if (t == 1023) off[N_NODES] = part[1023];
}

__global__ void fill_kernel(const int* __restrict__ ei, int* __restrict__ cur,
                            int* __restrict__ srt, const int* __restrict__ flags) {
    int i64 = flags[1];
    int e = blockIdx.x * 256 + threadIdx.x;
    int s, d;
    if (i64) { s = ei[2 * e]; d = ei[2 * N_EDGES + 2 * e]; }
    else     { s = ei[e];     d = ei[N_EDGES + e]; }
    int pos = atomicAdd(cur + d, 1);
    srt[pos] = s;
}

// agg row r, column `lane`: self term + CSR-gathered neighbors (4-way unrolled for MLP)
template<bool ISF>
__device__ __forceinline__ float gather_row(const void* __restrict__ h,
                                            const int* __restrict__ off,
                                            const int* __restrict__ srt,
                                            int r, int lane) {
    float acc = ld<ISF>(h, r * DD + lane);   // + x_i
    int k0 = off[r], k1 = off[r + 1];
    float a1 = 0.f, a2 = 0.f, a3 = 0.f;
    int k = k0;
    for (; k + 3 < k1; k += 4) {
        int s0 = srt[k], s1 = srt[k + 1], s2 = srt[k + 2], s3 = srt[k + 3];
        acc += ld<ISF>(h, s0 * DD + lane);
        a1  += ld<ISF>(h, s1 * DD + lane);
        a2  += ld<ISF>(h, s2 * DD + lane);
        a3  += ld<ISF>(h, s3 * DD + lane);
    }
    for (; k < k1; ++k) acc += ld<ISF>(h, srt[k] * DD + lane);
    return acc + ((a1 + a2) + a3);
}

// Fused: CSR gather (agg = x_i + sum x_j) -> LDS -> GEMM (W1,b1) -> hpre + BN sums.
// hsrc: layer1 = x (wire fmt per flags), layer2 = h1 fp32 (force_f32=1).
__global__ __launch_bounds__(256) void gather_gemm_stats_kernel(
    const void* __restrict__ hsrc, int force_f32,
    const int* __restrict__ off, const int* __restrict__ srt,
    const void* __restrict__ W, const void* __restrict__ bias,
    float* __restrict__ out_, float* __restrict__ sums, const int* __restrict__ flags)
{
    __shared__ float sIn[RPB][DD];           // 16 KB agg tile
    __shared__ float r1[4][DD], r2[4][DD];
    int tid = threadIdx.x;
    int lane = tid & 63, w = tid >> 6;
    int row0 = blockIdx.x * RPB;
    int isf = force_f32 ? 1 : flags[0];

    if (isf) {
        for (int j = 0; j < 16; ++j) {
            int r = row0 + w * 16 + j;
            sIn[w * 16 + j][lane] = (r < N_NODES) ? gather_row<true>(hsrc, off, srt, r, lane) : 0.f;
        }
    } else {
        for (int j = 0; j < 16; ++j) {
            int r = row0 + w * 16 + j;
            sIn[w * 16 + j][lane] = (r < N_NODES) ? gather_row<false>(hsrc, off, srt, r, lane) : 0.f;
        }
    }
    __syncthreads();

    float wcol[DD];                          // W[:,c], c = lane
    #pragma unroll
    for (int k = 0; k < DD; ++k) wcol[k] = loadF(W, k * DD + lane, isf);
    float bv = loadF(bias, lane, isf);

    float s1 = 0.f, s2 = 0.f;
    #pragma unroll 4
    for (int j = 0; j < 16; ++j) {
        int lr = w * 16 + j;
        float a0 = 0.f, a1 = 0.f, a2 = 0.f, a3 = 0.f;
        #pragma unroll
        for (int k = 0; k < DD; k += 4) {
            float4 a = *reinterpret_cast<const float4*>(&sIn[lr][k]);  // wave-uniform broadcast
            a0 += a.x * wcol[k];
            a1 += a.y * wcol[k + 1];
            a2 += a.z * wcol[k + 2];
            a3 += a.w * wcol[k + 3];
        }
        float acc = bv + ((a0 + a1) + (a2 + a3));
        int r = row0 + lr;
        if (r < N_NODES) {
            out_[r * DD + lane] = acc;
            s1 += acc;
            s2 += acc * acc;
        }
    }
    r1[w][lane] = s1; r2[w][lane] = s2;
    __syncthreads();
    if (w == 0) {
        atomicAdd(&sums[lane],      r1[0][lane] + r1[1][lane] + r1[2][lane] + r1[3][lane]);
        atomicAdd(&sums[64 + lane], r2[0][lane] + r2[1][lane] + r2[2][lane] + r2[3][lane]);
    }
}

// sums -> scale/shift (BN affine folded); re-zeroes sums for next layer.
__global__ void bn_params_kernel(float* __restrict__ sums,
                                 const void* __restrict__ gma, const void* __restrict__ beta,
                                 float* __restrict__ scsh, const int* __restrict__ flags) {
    int isf = flags[0];
    int c = threadIdx.x;   // 64 threads
    float S1 = sums[c];
    float S2 = sums[64 + c];
    float mean = S1 * (1.0f / N_NODES);
    float var  = S2 * (1.0f / N_NODES) - mean * mean;
    float scale = rsqrtf(var + BN_EPS) * loadF(gma, c, isf);
    scsh[c] = scale;
    scsh[DD + c] = loadF(beta, c, isf) - mean * scale;
    sums[c] = 0.0f;
    sums[64 + c] = 0.0f;
}

// h = relu(hpre*scale+shift); out = relu(h @ W2 + b2) -> fp32. In-place safe (LDS staged).
__global__ __launch_bounds__(256) void mlp2_kernel(
    const float* __restrict__ in_, const float* __restrict__ scsh,
    const void* __restrict__ W, const void* __restrict__ bias,
    float* __restrict__ oF, const int* __restrict__ flags)
{
    __shared__ float sIn[RPB][DD];
    int isf = flags[0];
    int tid = threadIdx.x;
    int c = tid & 63, g = tid >> 6;
    int row0 = blockIdx.x * RPB;

    #pragma unroll
    for (int j = 0; j < 4; ++j) {
        int lr = (tid >> 4) + 16 * j;
        int cc = (tid & 15) << 2;
        int r = row0 + lr;
        float4 v = make_float4(0.f, 0.f, 0.f, 0.f);
        if (r < N_NODES) {
            v = *reinterpret_cast<const float4*>(in_ + r * DD + cc);
            float4 sc = *reinterpret_cast<const float4*>(scsh + cc);
            float4 sh = *reinterpret_cast<const float4*>(scsh + DD + cc);
            v.x = fmaxf(v.x * sc.x + sh.x, 0.f);
            v.y = fmaxf(v.y * sc.y + sh.y, 0.f);
            v.z = fmaxf(v.z * sc.z + sh.z, 0.f);
            v.w = fmaxf(v.w * sc.w + sh.w, 0.f);
        }
        *reinterpret_cast<float4*>(&sIn[lr][cc]) = v;
    }
    __syncthreads();

    float wcol[DD];
    #pragma unroll
    for (int k = 0; k < DD; ++k) wcol[k] = loadF(W, k * DD + c, isf);
    float bv = loadF(bias, c, isf);

    #pragma unroll 4
    for (int j = 0; j < 16; ++j) {
        int lr = g * 16 + j;
        float a0 = 0.f, a1 = 0.f, a2 = 0.f, a3 = 0.f;
        #pragma unroll
        for (int k = 0; k < DD; k += 4) {
            float4 a = *reinterpret_cast<const float4*>(&sIn[lr][k]);
            a0 += a.x * wcol[k];
            a1 += a.y * wcol[k + 1];
            a2 += a.z * wcol[k + 2];
            a3 += a.w * wcol[k + 3];
        }
        float acc = fmaxf(bv + ((a0 + a1) + (a2 + a3)), 0.f);
        int r = row0 + lr;
        if (r < N_NODES) oF[r * DD + c] = acc;
    }
}

extern "C" void kernel_launch(void* const* d_in, const int* in_sizes, int n_in,
                              void* d_out, int out_size, void* d_ws, size_t ws_size,
                              hipStream_t stream)
{
    (void)in_sizes; (void)n_in; (void)out_size; (void)ws_size;
    const void* x  = d_in[0];
    const int* ei  = (const int*)d_in[1];
    const void* W1_0 = d_in[2];  const void* b1_0 = d_in[3];
    const void* g_0  = d_in[4];  const void* be_0 = d_in[5];
    const void* W2_0 = d_in[6];  const void* b2_0 = d_in[7];
    const void* W1_1 = d_in[8];  const void* b1_1 = d_in[9];
    const void* g_1  = d_in[10]; const void* be_1 = d_in[11];
    const void* W2_1 = d_in[12]; const void* b2_1 = d_in[13];

    float* wsf  = (float*)d_ws;
    float* sums = wsf;                    // 128
    float* scsh = wsf + 128;              // 128
    int*  flags = (int*)(wsf + 256);      // 2
    int*  cnt   = (int*)(wsf + 512);      // 50000
    int*  off   = cnt + 50048;            // 50001
    int*  cur   = off + 50064;            // 50000
    int*  srt   = cur + 50048;            // 800000
    float* O1   = (float*)d_out;                  // h1
    float* O2   = O1 + (size_t)N_NODES * DD;      // hpre scratch -> h2

    dim3 blk(256);

    // CSR build (shared by both layers)
    zero_kernel<<<(N_NODES + 255) / 256, blk, 0, stream>>>(cnt, sums);
    sniff_kernel<<<1, blk, 0, stream>>>(x, ei, flags);
    hist_kernel<<<N_EDGES / 256, blk, 0, stream>>>(ei, cnt, flags);
    scan_kernel<<<1, 1024, 0, stream>>>(cnt, off, cur);
    fill_kernel<<<N_EDGES / 256, blk, 0, stream>>>(ei, cur, srt, flags);

    // ---- layer 1 ----
    gather_gemm_stats_kernel<<<GBLOCKS, blk, 0, stream>>>(x, 0, off, srt, W1_0, b1_0,
                                                          O2, sums, flags);
    bn_params_kernel<<<1, 64, 0, stream>>>(sums, g_0, be_0, scsh, flags);
    mlp2_kernel<<<GBLOCKS, blk, 0, stream>>>(O2, scsh, W2_0, b2_0, O1, flags);

    // ---- layer 2 ----
    gather_gemm_stats_kernel<<<GBLOCKS, blk, 0, stream>>>(O1, 1, off, srt, W1_1, b1_1,
                                                          O2, sums, flags);
    bn_params_kernel<<<1, 64, 0, stream>>>(sums, g_1, be_1, scsh, flags);
    mlp2_kernel<<<GBLOCKS, blk, 0, stream>>>(O2, scsh, W2_1, b2_1, O2, flags);
}

// Round 6
// 391.258 us; speedup vs baseline: 1.3793x; 1.2363x over previous
//
#include <hip/hip_runtime.h>
#include <hip/hip_bf16.h>

#define N_NODES 50000
#define N_EDGES 800000
#define DD 64
#define RPB 64
#define GBLOCKS ((N_NODES + RPB - 1) / RPB)       // 782
#define SCAN_BLOCKS ((N_NODES + 255) / 256)       // 196
#define BN_EPS 1e-5f

// ws layout (fp32 words), ~3.8 MB total:
//   [0..127]  sums   [128..255] scsh   [256..] flags (isf, i64)
//   [512..]   cnt[50000], off[50001], cur[50000], bsum[256], srt[800000]
// d_out (fp32): O1 = h1 (layer-2 gather source), O2 = hpre scratch -> h2.

__device__ __forceinline__ float bf2f(unsigned short b) {
    return __uint_as_float(((unsigned)b) << 16);
}
__device__ __forceinline__ float loadF(const void* p, int i, int isf) {
    return isf ? ((const float*)p)[i] : bf2f(((const unsigned short*)p)[i]);
}
template<bool ISF>
__device__ __forceinline__ float ld(const void* p, int i) {
    return ISF ? ((const float*)p)[i] : bf2f(((const unsigned short*)p)[i]);
}

// zero CSR counts + BN sums
__global__ void zero_kernel(int* __restrict__ cnt, float* __restrict__ sums) {
    int i = blockIdx.x * 256 + threadIdx.x;
    if (i < N_NODES) cnt[i] = 0;
    if (i < 128) sums[i] = 0.0f;
}

// Detect wire formats. flags[0]=1 iff floats fp32; flags[1]=1 iff ints int64.
__global__ void sniff_kernel(const void* __restrict__ x, const int* __restrict__ ei,
                             int* __restrict__ flags) {
    __shared__ int cntF, cntI;
    int t = threadIdx.x;
    if (t == 0) { cntF = 0; cntI = 0; }
    __syncthreads();
    unsigned short w = ((const unsigned short*)x)[2 * t];
    int e = (w >> 7) & 0xFF;
    if (e >= 0x70 && e <= 0x8F) atomicAdd(&cntF, 1);        // bf16-plausible exponent
    if (t < 128 && ei[2 * t + 1] == 0) atomicAdd(&cntI, 1); // int64 high words are 0
    __syncthreads();
    if (t == 0) {
        flags[0] = (cntF < 128) ? 1 : 0;
        flags[1] = (cntI > 64) ? 1 : 0;
    }
}

__global__ void hist_kernel(const int* __restrict__ ei, int* __restrict__ cnt,
                            const int* __restrict__ flags) {
    int i64 = flags[1];
    int e = blockIdx.x * 256 + threadIdx.x;
    int d = i64 ? ei[2 * N_EDGES + 2 * e] : ei[N_EDGES + e];
    atomicAdd(cnt + d, 1);
}

// ---- hierarchical scan: A (block-local exclusive), B (scan block sums), C (add base) ----
__global__ __launch_bounds__(256) void scanA_kernel(const int* __restrict__ cnt,
                                                    int* __restrict__ off,
                                                    int* __restrict__ bsum) {
    __shared__ int tmp[256];
    int t = threadIdx.x;
    int i = blockIdx.x * 256 + t;
    int v = (i < N_NODES) ? cnt[i] : 0;
    tmp[t] = v;
    __syncthreads();
    #pragma unroll
    for (int d = 1; d < 256; d <<= 1) {     // Hillis-Steele inclusive
        int u = (t >= d) ? tmp[t - d] : 0;
        __syncthreads();
        tmp[t] += u;
        __syncthreads();
    }
    if (i < N_NODES) off[i] = tmp[t] - v;   // block-local exclusive
    if (t == 255) bsum[blockIdx.x] = tmp[255];
}

__global__ __launch_bounds__(256) void scanB_kernel(int* __restrict__ bsum,
                                                    int* __restrict__ off) {
    __shared__ int tmp[256];
    int t = threadIdx.x;
    int v = (t < SCAN_BLOCKS) ? bsum[t] : 0;
    tmp[t] = v;
    __syncthreads();
    #pragma unroll
    for (int d = 1; d < 256; d <<= 1) {
        int u = (t >= d) ? tmp[t - d] : 0;
        __syncthreads();
        tmp[t] += u;
        __syncthreads();
    }
    if (t < SCAN_BLOCKS) bsum[t] = tmp[t] - v;   // exclusive base per block
    if (t == 255) off[N_NODES] = tmp[255];       // total (= N_EDGES)
}

__global__ __launch_bounds__(256) void scanC_kernel(const int* __restrict__ bsum,
                                                    int* __restrict__ off,
                                                    int* __restrict__ cur) {
    int i = blockIdx.x * 256 + threadIdx.x;
    if (i < N_NODES) {
        int o = off[i] + bsum[blockIdx.x];
        off[i] = o;
        cur[i] = o;
    }
}

__global__ void fill_kernel(const int* __restrict__ ei, int* __restrict__ cur,
                            int* __restrict__ srt, const int* __restrict__ flags) {
    int i64 = flags[1];
    int e = blockIdx.x * 256 + threadIdx.x;
    int s, d;
    if (i64) { s = ei[2 * e]; d = ei[2 * N_EDGES + 2 * e]; }
    else     { s = ei[e];     d = ei[N_EDGES + e]; }
    int pos = atomicAdd(cur + d, 1);
    srt[pos] = s;
}

// agg row r, column `lane`: self term + CSR-gathered neighbors (4-way unrolled)
template<bool ISF>
__device__ __forceinline__ float gather_row(const void* __restrict__ h,
                                            const int* __restrict__ off,
                                            const int* __restrict__ srt,
                                            int r, int lane) {
    float acc = ld<ISF>(h, r * DD + lane);   // + x_i
    int k0 = off[r], k1 = off[r + 1];
    float a1 = 0.f, a2 = 0.f, a3 = 0.f;
    int k = k0;
    for (; k + 3 < k1; k += 4) {
        int s0 = srt[k], s1 = srt[k + 1], s2 = srt[k + 2], s3 = srt[k + 3];
        acc += ld<ISF>(h, s0 * DD + lane);
        a1  += ld<ISF>(h, s1 * DD + lane);
        a2  += ld<ISF>(h, s2 * DD + lane);
        a3  += ld<ISF>(h, s3 * DD + lane);
    }
    for (; k < k1; ++k) acc += ld<ISF>(h, srt[k] * DD + lane);
    return acc + ((a1 + a2) + a3);
}

// Fused: CSR gather (agg = x_i + sum x_j) -> LDS -> GEMM (W1,b1) -> hpre + BN sums.
__global__ __launch_bounds__(256) void gather_gemm_stats_kernel(
    const void* __restrict__ hsrc, int force_f32,
    const int* __restrict__ off, const int* __restrict__ srt,
    const void* __restrict__ W, const void* __restrict__ bias,
    float* __restrict__ out_, float* __restrict__ sums, const int* __restrict__ flags)
{
    __shared__ float sIn[RPB][DD];           // 16 KB agg tile
    __shared__ float r1[4][DD], r2[4][DD];
    int tid = threadIdx.x;
    int lane = tid & 63, w = tid >> 6;
    int row0 = blockIdx.x * RPB;
    int isf = force_f32 ? 1 : flags[0];

    if (isf) {
        for (int j = 0; j < 16; ++j) {
            int r = row0 + w * 16 + j;
            sIn[w * 16 + j][lane] = (r < N_NODES) ? gather_row<true>(hsrc, off, srt, r, lane) : 0.f;
        }
    } else {
        for (int j = 0; j < 16; ++j) {
            int r = row0 + w * 16 + j;
            sIn[w * 16 + j][lane] = (r < N_NODES) ? gather_row<false>(hsrc, off, srt, r, lane) : 0.f;
        }
    }
    __syncthreads();

    float wcol[DD];                          // W[:,c], c = lane
    #pragma unroll
    for (int k = 0; k < DD; ++k) wcol[k] = loadF(W, k * DD + lane, isf);
    float bv = loadF(bias, lane, isf);

    float s1 = 0.f, s2 = 0.f;
    #pragma unroll 4
    for (int j = 0; j < 16; ++j) {
        int lr = w * 16 + j;
        float a0 = 0.f, a1 = 0.f, a2 = 0.f, a3 = 0.f;
        #pragma unroll
        for (int k = 0; k < DD; k += 4) {
            float4 a = *reinterpret_cast<const float4*>(&sIn[lr][k]);  // wave-uniform broadcast
            a0 += a.x * wcol[k];
            a1 += a.y * wcol[k + 1];
            a2 += a.z * wcol[k + 2];
            a3 += a.w * wcol[k + 3];
        }
        float acc = bv + ((a0 + a1) + (a2 + a3));
        int r = row0 + lr;
        if (r < N_NODES) {
            out_[r * DD + lane] = acc;
            s1 += acc;
            s2 += acc * acc;
        }
    }
    r1[w][lane] = s1; r2[w][lane] = s2;
    __syncthreads();
    if (w == 0) {
        atomicAdd(&sums[lane],      r1[0][lane] + r1[1][lane] + r1[2][lane] + r1[3][lane]);
        atomicAdd(&sums[64 + lane], r2[0][lane] + r2[1][lane] + r2[2][lane] + r2[3][lane]);
    }
}

// sums -> scale/shift (BN affine folded); re-zeroes sums for next layer.
__global__ void bn_params_kernel(float* __restrict__ sums,
                                 const void* __restrict__ gma, const void* __restrict__ beta,
                                 float* __restrict__ scsh, const int* __restrict__ flags) {
    int isf = flags[0];
    int c = threadIdx.x;   // 64 threads
    float S1 = sums[c];
    float S2 = sums[64 + c];
    float mean = S1 * (1.0f / N_NODES);
    float var  = S2 * (1.0f / N_NODES) - mean * mean;
    float scale = rsqrtf(var + BN_EPS) * loadF(gma, c, isf);
    scsh[c] = scale;
    scsh[DD + c] = loadF(beta, c, isf) - mean * scale;
    sums[c] = 0.0f;
    sums[64 + c] = 0.0f;
}

// h = relu(hpre*scale+shift); out = relu(h @ W2 + b2) -> fp32. In-place safe (LDS staged).
__global__ __launch_bounds__(256) void mlp2_kernel(
    const float* __restrict__ in_, const float* __restrict__ scsh,
    const void* __restrict__ W, const void* __restrict__ bias,
    float* __restrict__ oF, const int* __restrict__ flags)
{
    __shared__ float sIn[RPB][DD];
    int isf = flags[0];
    int tid = threadIdx.x;
    int c = tid & 63, g = tid >> 6;
    int row0 = blockIdx.x * RPB;

    #pragma unroll
    for (int j = 0; j < 4; ++j) {
        int lr = (tid >> 4) + 16 * j;
        int cc = (tid & 15) << 2;
        int r = row0 + lr;
        float4 v = make_float4(0.f, 0.f, 0.f, 0.f);
        if (r < N_NODES) {
            v = *reinterpret_cast<const float4*>(in_ + r * DD + cc);
            float4 sc = *reinterpret_cast<const float4*>(scsh + cc);
            float4 sh = *reinterpret_cast<const float4*>(scsh + DD + cc);
            v.x = fmaxf(v.x * sc.x + sh.x, 0.f);
            v.y = fmaxf(v.y * sc.y + sh.y, 0.f);
            v.z = fmaxf(v.z * sc.z + sh.z, 0.f);
            v.w = fmaxf(v.w * sc.w + sh.w, 0.f);
        }
        *reinterpret_cast<float4*>(&sIn[lr][cc]) = v;
    }
    __syncthreads();

    float wcol[DD];
    #pragma unroll
    for (int k = 0; k < DD; ++k) wcol[k] = loadF(W, k * DD + c, isf);
    float bv = loadF(bias, c, isf);

    #pragma unroll 4
    for (int j = 0; j < 16; ++j) {
        int lr = g * 16 + j;
        float a0 = 0.f, a1 = 0.f, a2 = 0.f, a3 = 0.f;
        #pragma unroll
        for (int k = 0; k < DD; k += 4) {
            float4 a = *reinterpret_cast<const float4*>(&sIn[lr][k]);
            a0 += a.x * wcol[k];
            a1 += a.y * wcol[k + 1];
            a2 += a.z * wcol[k + 2];
            a3 += a.w * wcol[k + 3];
        }
        float acc = fmaxf(bv + ((a0 + a1) + (a2 + a3)), 0.f);
        int r = row0 + lr;
        if (r < N_NODES) oF[r * DD + c] = acc;
    }
}

extern "C" void kernel_launch(void* const* d_in, const int* in_sizes, int n_in,
                              void* d_out, int out_size, void* d_ws, size_t ws_size,
                              hipStream_t stream)
{
    (void)in_sizes; (void)n_in; (void)out_size; (void)ws_size;
    const void* x  = d_in[0];
    const int* ei  = (const int*)d_in[1];
    const void* W1_0 = d_in[2];  const void* b1_0 = d_in[3];
    const void* g_0  = d_in[4];  const void* be_0 = d_in[5];
    const void* W2_0 = d_in[6];  const void* b2_0 = d_in[7];
    const void* W1_1 = d_in[8];  const void* b1_1 = d_in[9];
    const void* g_1  = d_in[10]; const void* be_1 = d_in[11];
    const void* W2_1 = d_in[12]; const void* b2_1 = d_in[13];

    float* wsf  = (float*)d_ws;
    float* sums = wsf;                    // 128
    float* scsh = wsf + 128;              // 128
    int*  flags = (int*)(wsf + 256);      // 2
    int*  cnt   = (int*)(wsf + 512);      // 50000
    int*  off   = cnt + 50048;            // 50001
    int*  cur   = off + 50064;            // 50000
    int*  bsum  = cur + 50048;            // 256
    int*  srt   = bsum + 256;             // 800000
    float* O1   = (float*)d_out;                  // h1
    float* O2   = O1 + (size_t)N_NODES * DD;      // hpre scratch -> h2

    dim3 blk(256);

    // CSR build (shared by both layers)
    zero_kernel<<<(N_NODES + 255) / 256, blk, 0, stream>>>(cnt, sums);
    sniff_kernel<<<1, blk, 0, stream>>>(x, ei, flags);
    hist_kernel<<<N_EDGES / 256, blk, 0, stream>>>(ei, cnt, flags);
    scanA_kernel<<<SCAN_BLOCKS, blk, 0, stream>>>(cnt, off, bsum);
    scanB_kernel<<<1, blk, 0, stream>>>(bsum, off);
    scanC_kernel<<<SCAN_BLOCKS, blk, 0, stream>>>(bsum, off, cur);
    fill_kernel<<<N_EDGES / 256, blk, 0, stream>>>(ei, cur, srt, flags);

    // ---- layer 1 ----
    gather_gemm_stats_kernel<<<GBLOCKS, blk, 0, stream>>>(x, 0, off, srt, W1_0, b1_0,
                                                          O2, sums, flags);
    bn_params_kernel<<<1, 64, 0, stream>>>(sums, g_0, be_0, scsh, flags);
    mlp2_kernel<<<GBLOCKS, blk, 0, stream>>>(O2, scsh, W2_0, b2_0, O1, flags);

    // ---- layer 2 ----
    gather_gemm_stats_kernel<<<GBLOCKS, blk, 0, stream>>>(O1, 1, off, srt, W1_1, b1_1,
                                                          O2, sums, flags);
    bn_params_kernel<<<1, 64, 0, stream>>>(sums, g_1, be_1, scsh, flags);
    mlp2_kernel<<<GBLOCKS, blk, 0, stream>>>(O2, scsh, W2_1, b2_1, O2, flags);
}

// Round 7
// 359.039 us; speedup vs baseline: 1.5031x; 1.0897x over previous
//
#include <hip/hip_runtime.h>
#include <hip/hip_bf16.h>

#define N_NODES 50000
#define N_EDGES 800000
#define DD 64
#define RPB 64
#define GBLOCKS ((N_NODES + RPB - 1) / RPB)       // 782
#define SCAN_BLOCKS ((N_NODES + 255) / 256)       // 196
#define BN_EPS 1e-5f

// ws layout (fp32 words):
//   [0..127] sums   [128..255] scsh   [256..] flags (isf, i64)
//   [512..]  cnt[50000], off[50001], cur[50000], bsum[256], srt[800000]
// d_out (fp32): O1 = h1 (layer-2 gather source), O2 = hpre scratch -> h2.

__device__ __forceinline__ float bf2f(unsigned short b) {
    return __uint_as_float(((unsigned)b) << 16);
}
__device__ __forceinline__ float loadF(const void* p, int i, int isf) {
    return isf ? ((const float*)p)[i] : bf2f(((const unsigned short*)p)[i]);
}
template<bool ISF>
__device__ __forceinline__ float4 ld4(const void* p, int i) {  // i = float idx, 4-aligned
    if (ISF) return *reinterpret_cast<const float4*>((const float*)p + i);
    ushort4 u = *reinterpret_cast<const ushort4*>((const unsigned short*)p + i);
    return make_float4(bf2f(u.x), bf2f(u.y), bf2f(u.z), bf2f(u.w));
}

// zero CSR counts + BN sums; block 0 sniffs wire formats.
__global__ void init_kernel(const void* __restrict__ x, const int* __restrict__ ei,
                            int* __restrict__ flags, int* __restrict__ cnt,
                            float* __restrict__ sums) {
    int i = blockIdx.x * 256 + threadIdx.x;
    if (i < N_NODES) cnt[i] = 0;
    if (i < 128) sums[i] = 0.0f;
    if (blockIdx.x == 0) {
        __shared__ int cntF, cntI;
        int t = threadIdx.x;
        if (t == 0) { cntF = 0; cntI = 0; }
        __syncthreads();
        unsigned short w = ((const unsigned short*)x)[2 * t];
        int e = (w >> 7) & 0xFF;
        if (e >= 0x70 && e <= 0x8F) atomicAdd(&cntF, 1);        // bf16-plausible exponent
        if (t < 128 && ei[2 * t + 1] == 0) atomicAdd(&cntI, 1); // int64 high words are 0
        __syncthreads();
        if (t == 0) {
            flags[0] = (cntF < 128) ? 1 : 0;
            flags[1] = (cntI > 64) ? 1 : 0;
        }
    }
}

__global__ void hist_kernel(const int* __restrict__ ei, int* __restrict__ cnt,
                            const int* __restrict__ flags) {
    int i64 = flags[1];
    int e = blockIdx.x * 256 + threadIdx.x;
    int d = i64 ? ei[2 * N_EDGES + 2 * e] : ei[N_EDGES + e];
    atomicAdd(cnt + d, 1);
}

// ---- hierarchical scan ----
__global__ __launch_bounds__(256) void scanA_kernel(const int* __restrict__ cnt,
                                                    int* __restrict__ off,
                                                    int* __restrict__ bsum) {
    __shared__ int tmp[256];
    int t = threadIdx.x;
    int i = blockIdx.x * 256 + t;
    int v = (i < N_NODES) ? cnt[i] : 0;
    tmp[t] = v;
    __syncthreads();
    #pragma unroll
    for (int d = 1; d < 256; d <<= 1) {
        int u = (t >= d) ? tmp[t - d] : 0;
        __syncthreads();
        tmp[t] += u;
        __syncthreads();
    }
    if (i < N_NODES) off[i] = tmp[t] - v;
    if (t == 255) bsum[blockIdx.x] = tmp[255];
}

__global__ __launch_bounds__(256) void scanB_kernel(int* __restrict__ bsum,
                                                    int* __restrict__ off) {
    __shared__ int tmp[256];
    int t = threadIdx.x;
    int v = (t < SCAN_BLOCKS) ? bsum[t] : 0;
    tmp[t] = v;
    __syncthreads();
    #pragma unroll
    for (int d = 1; d < 256; d <<= 1) {
        int u = (t >= d) ? tmp[t - d] : 0;
        __syncthreads();
        tmp[t] += u;
        __syncthreads();
    }
    if (t < SCAN_BLOCKS) bsum[t] = tmp[t] - v;
    if (t == 255) off[N_NODES] = tmp[255];
}

__global__ __launch_bounds__(256) void scanC_kernel(const int* __restrict__ bsum,
                                                    int* __restrict__ off,
                                                    int* __restrict__ cur) {
    int i = blockIdx.x * 256 + threadIdx.x;
    if (i < N_NODES) {
        int o = off[i] + bsum[blockIdx.x];
        off[i] = o;
        cur[i] = o;
    }
}

__global__ void fill_kernel(const int* __restrict__ ei, int* __restrict__ cur,
                            int* __restrict__ srt, const int* __restrict__ flags) {
    int i64 = flags[1];
    int e = blockIdx.x * 256 + threadIdx.x;
    int s, d;
    if (i64) { s = ei[2 * e]; d = ei[2 * N_EDGES + 2 * e]; }
    else     { s = ei[e];     d = ei[N_EDGES + e]; }
    int pos = atomicAdd(cur + d, 1);
    srt[pos] = s;
}

// Per-row float4 gather: lanes = (nb = lane>>4) neighbor slot x (ch = lane&15) chunk.
// Returns per-lane partial float4 (caller reduces across nb and adds self term).
template<bool ISF>
__device__ __forceinline__ float4 gather_row4(const void* __restrict__ h,
                                              const int* __restrict__ off,
                                              const int* __restrict__ srt,
                                              int r, int lane, int nb, int ch) {
    float4 acc = make_float4(0.f, 0.f, 0.f, 0.f);
    float4 acc2 = make_float4(0.f, 0.f, 0.f, 0.f);
    int k0 = off[r], k1 = off[r + 1];
    for (int kb = k0; kb < k1; kb += 64) {
        int nload = min(64, k1 - kb);
        int sv = (lane < nload) ? srt[kb + lane] : 0;
        int nfull = nload >> 2;
        int b = 0;
        for (; b + 2 <= nfull; b += 2) {
            int s0 = __shfl(sv, 4 * b + nb, 64);
            int s1 = __shfl(sv, 4 * b + 4 + nb, 64);
            float4 v0 = ld4<ISF>(h, s0 * DD + 4 * ch);
            float4 v1 = ld4<ISF>(h, s1 * DD + 4 * ch);
            acc.x += v0.x; acc.y += v0.y; acc.z += v0.z; acc.w += v0.w;
            acc2.x += v1.x; acc2.y += v1.y; acc2.z += v1.z; acc2.w += v1.w;
        }
        if (b < nfull) {
            int s0 = __shfl(sv, 4 * b + nb, 64);
            float4 v0 = ld4<ISF>(h, s0 * DD + 4 * ch);
            acc.x += v0.x; acc.y += v0.y; acc.z += v0.z; acc.w += v0.w;
        }
        int rem = nload & 3;
        if (rem) {
            int s0 = __shfl(sv, 4 * nfull + nb, 64);
            if (nb < rem) {
                float4 v0 = ld4<ISF>(h, s0 * DD + 4 * ch);
                acc.x += v0.x; acc.y += v0.y; acc.z += v0.z; acc.w += v0.w;
            }
        }
    }
    acc.x += acc2.x; acc.y += acc2.y; acc.z += acc2.z; acc.w += acc2.w;
    return acc;
}

// Fused: CSR float4-gather (agg = x_i + sum x_j) -> LDS -> GEMM (W1,b1) -> hpre + BN sums.
// 512 threads = 8 waves; each wave gathers 8 rows; GEMM: each thread 8 rows, col = lane.
__global__ __launch_bounds__(512) void gather_gemm_stats_kernel(
    const void* __restrict__ hsrc, int force_f32,
    const int* __restrict__ off, const int* __restrict__ srt,
    const void* __restrict__ W, const void* __restrict__ bias,
    float* __restrict__ out_, float* __restrict__ sums, const int* __restrict__ flags)
{
    __shared__ float sIn[RPB][DD];            // 16 KB agg tile
    __shared__ float r1[8][DD], r2[8][DD];    // 4 KB stats
    int tid = threadIdx.x;
    int lane = tid & 63, w = tid >> 6;        // wave 0..7
    int nb = lane >> 4, ch = lane & 15;
    int row0 = blockIdx.x * RPB;
    int isf = force_f32 ? 1 : flags[0];

    for (int j = 0; j < 8; ++j) {
        int lr = w * 8 + j;
        int r = row0 + lr;
        float4 acc = make_float4(0.f, 0.f, 0.f, 0.f);
        if (r < N_NODES) {
            acc = isf ? gather_row4<true>(hsrc, off, srt, r, lane, nb, ch)
                      : gather_row4<false>(hsrc, off, srt, r, lane, nb, ch);
        }
        // reduce across nb groups (lanes ^16, ^32)
        acc.x += __shfl_xor(acc.x, 16, 64);
        acc.y += __shfl_xor(acc.y, 16, 64);
        acc.z += __shfl_xor(acc.z, 16, 64);
        acc.w += __shfl_xor(acc.w, 16, 64);
        acc.x += __shfl_xor(acc.x, 32, 64);
        acc.y += __shfl_xor(acc.y, 32, 64);
        acc.z += __shfl_xor(acc.z, 32, 64);
        acc.w += __shfl_xor(acc.w, 32, 64);
        if (nb == 0) {
            if (r < N_NODES) {
                float4 self = isf ? ld4<true>(hsrc, r * DD + 4 * ch)
                                  : ld4<false>(hsrc, r * DD + 4 * ch);
                acc.x += self.x; acc.y += self.y; acc.z += self.z; acc.w += self.w;
            }
            *reinterpret_cast<float4*>(&sIn[lr][4 * ch]) = acc;
        }
    }
    __syncthreads();

    float wcol[DD];                           // W[:,c], c = lane
    #pragma unroll
    for (int k = 0; k < DD; ++k) wcol[k] = loadF(W, k * DD + lane, isf);
    float bv = loadF(bias, lane, isf);

    float s1 = 0.f, s2 = 0.f;
    #pragma unroll 4
    for (int j = 0; j < 8; ++j) {
        int lr = w * 8 + j;
        float a0 = 0.f, a1 = 0.f, a2 = 0.f, a3 = 0.f;
        #pragma unroll
        for (int k = 0; k < DD; k += 4) {
            float4 a = *reinterpret_cast<const float4*>(&sIn[lr][k]);  // wave-uniform broadcast
            a0 += a.x * wcol[k];
            a1 += a.y * wcol[k + 1];
            a2 += a.z * wcol[k + 2];
            a3 += a.w * wcol[k + 3];
        }
        float acc = bv + ((a0 + a1) + (a2 + a3));
        int r = row0 + lr;
        if (r < N_NODES) {
            out_[r * DD + lane] = acc;
            s1 += acc;
            s2 += acc * acc;
        }
    }
    r1[w][lane] = s1; r2[w][lane] = s2;
    __syncthreads();
    if (w == 0) {
        float t1 = 0.f, t2 = 0.f;
        #pragma unroll
        for (int q = 0; q < 8; ++q) { t1 += r1[q][lane]; t2 += r2[q][lane]; }
        atomicAdd(&sums[lane], t1);
        atomicAdd(&sums[64 + lane], t2);
    }
}

// sums -> scale/shift (BN affine folded); re-zeroes sums for next layer.
__global__ void bn_params_kernel(float* __restrict__ sums,
                                 const void* __restrict__ gma, const void* __restrict__ beta,
                                 float* __restrict__ scsh, const int* __restrict__ flags) {
    int isf = flags[0];
    int c = threadIdx.x;   // 64 threads
    float S1 = sums[c];
    float S2 = sums[64 + c];
    float mean = S1 * (1.0f / N_NODES);
    float var  = S2 * (1.0f / N_NODES) - mean * mean;
    float scale = rsqrtf(var + BN_EPS) * loadF(gma, c, isf);
    scsh[c] = scale;
    scsh[DD + c] = loadF(beta, c, isf) - mean * scale;
    sums[c] = 0.0f;
    sums[64 + c] = 0.0f;
}

// h = relu(hpre*scale+shift); out = relu(h @ W2 + b2) -> fp32. In-place safe (LDS staged).
__global__ __launch_bounds__(256) void mlp2_kernel(
    const float* __restrict__ in_, const float* __restrict__ scsh,
    const void* __restrict__ W, const void* __restrict__ bias,
    float* __restrict__ oF, const int* __restrict__ flags)
{
    __shared__ float sIn[RPB][DD];
    int isf = flags[0];
    int tid = threadIdx.x;
    int c = tid & 63, g = tid >> 6;
    int row0 = blockIdx.x * RPB;

    #pragma unroll
    for (int j = 0; j < 4; ++j) {
        int lr = (tid >> 4) + 16 * j;
        int cc = (tid & 15) << 2;
        int r = row0 + lr;
        float4 v = make_float4(0.f, 0.f, 0.f, 0.f);
        if (r < N_NODES) {
            v = *reinterpret_cast<const float4*>(in_ + r * DD + cc);
            float4 sc = *reinterpret_cast<const float4*>(scsh + cc);
            float4 sh = *reinterpret_cast<const float4*>(scsh + DD + cc);
            v.x = fmaxf(v.x * sc.x + sh.x, 0.f);
            v.y = fmaxf(v.y * sc.y + sh.y, 0.f);
            v.z = fmaxf(v.z * sc.z + sh.z, 0.f);
            v.w = fmaxf(v.w * sc.w + sh.w, 0.f);
        }
        *reinterpret_cast<float4*>(&sIn[lr][cc]) = v;
    }
    __syncthreads();

    float wcol[DD];
    #pragma unroll
    for (int k = 0; k < DD; ++k) wcol[k] = loadF(W, k * DD + c, isf);
    float bv = loadF(bias, c, isf);

    #pragma unroll 4
    for (int j = 0; j < 16; ++j) {
        int lr = g * 16 + j;
        float a0 = 0.f, a1 = 0.f, a2 = 0.f, a3 = 0.f;
        #pragma unroll
        for (int k = 0; k < DD; k += 4) {
            float4 a = *reinterpret_cast<const float4*>(&sIn[lr][k]);
            a0 += a.x * wcol[k];
            a1 += a.y * wcol[k + 1];
            a2 += a.z * wcol[k + 2];
            a3 += a.w * wcol[k + 3];
        }
        float acc = fmaxf(bv + ((a0 + a1) + (a2 + a3)), 0.f);
        int r = row0 + lr;
        if (r < N_NODES) oF[r * DD + c] = acc;
    }
}

extern "C" void kernel_launch(void* const* d_in, const int* in_sizes, int n_in,
                              void* d_out, int out_size, void* d_ws, size_t ws_size,
                              hipStream_t stream)
{
    (void)in_sizes; (void)n_in; (void)out_size; (void)ws_size;
    const void* x  = d_in[0];
    const int* ei  = (const int*)d_in[1];
    const void* W1_0 = d_in[2];  const void* b1_0 = d_in[3];
    const void* g_0  = d_in[4];  const void* be_0 = d_in[5];
    const void* W2_0 = d_in[6];  const void* b2_0 = d_in[7];
    const void* W1_1 = d_in[8];  const void* b1_1 = d_in[9];
    const void* g_1  = d_in[10]; const void* be_1 = d_in[11];
    const void* W2_1 = d_in[12]; const void* b2_1 = d_in[13];

    float* wsf  = (float*)d_ws;
    float* sums = wsf;                    // 128
    float* scsh = wsf + 128;              // 128
    int*  flags = (int*)(wsf + 256);      // 2
    int*  cnt   = (int*)(wsf + 512);      // 50000
    int*  off   = cnt + 50048;            // 50001
    int*  cur   = off + 50064;            // 50000
    int*  bsum  = cur + 50048;            // 256
    int*  srt   = bsum + 256;             // 800000
    float* O1   = (float*)d_out;                  // h1
    float* O2   = O1 + (size_t)N_NODES * DD;      // hpre scratch -> h2

    dim3 blk(256);

    // CSR build (shared by both layers)
    init_kernel<<<SCAN_BLOCKS, blk, 0, stream>>>(x, ei, flags, cnt, sums);
    hist_kernel<<<N_EDGES / 256, blk, 0, stream>>>(ei, cnt, flags);
    scanA_kernel<<<SCAN_BLOCKS, blk, 0, stream>>>(cnt, off, bsum);
    scanB_kernel<<<1, blk, 0, stream>>>(bsum, off);
    scanC_kernel<<<SCAN_BLOCKS, blk, 0, stream>>>(bsum, off, cur);
    fill_kernel<<<N_EDGES / 256, blk, 0, stream>>>(ei, cur, srt, flags);

    // ---- layer 1 ----
    gather_gemm_stats_kernel<<<GBLOCKS, 512, 0, stream>>>(x, 0, off, srt, W1_0, b1_0,
                                                          O2, sums, flags);
    bn_params_kernel<<<1, 64, 0, stream>>>(sums, g_0, be_0, scsh, flags);
    mlp2_kernel<<<GBLOCKS, blk, 0, stream>>>(O2, scsh, W2_0, b2_0, O1, flags);

    // ---- layer 2 ----
    gather_gemm_stats_kernel<<<GBLOCKS, 512, 0, stream>>>(O1, 1, off, srt, W1_1, b1_1,
                                                          O2, sums, flags);
    bn_params_kernel<<<1, 64, 0, stream>>>(sums, g_1, be_1, scsh, flags);
    mlp2_kernel<<<GBLOCKS, blk, 0, stream>>>(O2, scsh, W2_1, b2_1, O2, flags);
}

// Round 8
// 350.724 us; speedup vs baseline: 1.5387x; 1.0237x over previous
//
#include <hip/hip_runtime.h>
#include <hip/hip_bf16.h>

#define N_NODES 50000
#define N_EDGES 800000
#define DD 64
#define RPB 64
#define GBLOCKS ((N_NODES + RPB - 1) / RPB)       // 782
#define SCAN_BLOCKS ((N_NODES + 255) / 256)       // 196
#define BN_EPS 1e-5f

// ws layout (fp32 words), ~10.2 MB total:
//   [0..127] sums   [128..255] scsh   [256..] flags (isf, i64)
//   [512..]  cnt[50000], off[50001], cur[50000], bsum[256], srt[800000]
//   then xb: 3.2M bf16 (gather shadow: bf16(x) for layer 1, bf16(h1) for layer 2)
// d_out (fp32): O1 = h1 (fp32 self-term source), O2 = hpre scratch -> h2.

__device__ __forceinline__ float bf2f(unsigned short b) {
    return __uint_as_float(((unsigned)b) << 16);
}
__device__ __forceinline__ float loadF(const void* p, int i, int isf) {
    return isf ? ((const float*)p)[i] : bf2f(((const unsigned short*)p)[i]);
}
template<bool ISF>
__device__ __forceinline__ float4 ld4(const void* p, int i) {  // i = elem idx, 4-aligned
    if (ISF) return *reinterpret_cast<const float4*>((const float*)p + i);
    ushort4 u = *reinterpret_cast<const ushort4*>((const unsigned short*)p + i);
    return make_float4(bf2f(u.x), bf2f(u.y), bf2f(u.z), bf2f(u.w));
}
// accumulate 8 bf16 (packed in uint4) into two float4s
__device__ __forceinline__ void acc8(float4& a, float4& b, uint4 u) {
    a.x += __uint_as_float(u.x << 16);
    a.y += __uint_as_float(u.x & 0xFFFF0000u);
    a.z += __uint_as_float(u.y << 16);
    a.w += __uint_as_float(u.y & 0xFFFF0000u);
    b.x += __uint_as_float(u.z << 16);
    b.y += __uint_as_float(u.z & 0xFFFF0000u);
    b.z += __uint_as_float(u.w << 16);
    b.w += __uint_as_float(u.w & 0xFFFF0000u);
}

// zero CSR counts + BN sums; block 0 sniffs wire formats.
__global__ void init_kernel(const void* __restrict__ x, const int* __restrict__ ei,
                            int* __restrict__ flags, int* __restrict__ cnt,
                            float* __restrict__ sums) {
    int i = blockIdx.x * 256 + threadIdx.x;
    if (i < N_NODES) cnt[i] = 0;
    if (i < 128) sums[i] = 0.0f;
    if (blockIdx.x == 0) {
        __shared__ int cntF, cntI;
        int t = threadIdx.x;
        if (t == 0) { cntF = 0; cntI = 0; }
        __syncthreads();
        unsigned short w = ((const unsigned short*)x)[2 * t];
        int e = (w >> 7) & 0xFF;
        if (e >= 0x70 && e <= 0x8F) atomicAdd(&cntF, 1);        // bf16-plausible exponent
        if (t < 128 && ei[2 * t + 1] == 0) atomicAdd(&cntI, 1); // int64 high words are 0
        __syncthreads();
        if (t == 0) {
            flags[0] = (cntF < 128) ? 1 : 0;
            flags[1] = (cntI > 64) ? 1 : 0;
        }
    }
}

// xb[i] = bf16(x[i]), 8 elems/thread
__global__ void cast_kernel(const void* __restrict__ x, unsigned short* __restrict__ xb,
                            const int* __restrict__ flags) {
    int isf = flags[0];
    int i = (blockIdx.x * 256 + threadIdx.x) * 8;
    if (i >= N_NODES * DD) return;
    float4 a = ld4<true>(x, 0), b = a;
    if (isf) {
        a = *reinterpret_cast<const float4*>((const float*)x + i);
        b = *reinterpret_cast<const float4*>((const float*)x + i + 4);
        ushort4 o0, o1;
        o0.x = __bfloat16_as_ushort(__float2bfloat16(a.x));
        o0.y = __bfloat16_as_ushort(__float2bfloat16(a.y));
        o0.z = __bfloat16_as_ushort(__float2bfloat16(a.z));
        o0.w = __bfloat16_as_ushort(__float2bfloat16(a.w));
        o1.x = __bfloat16_as_ushort(__float2bfloat16(b.x));
        o1.y = __bfloat16_as_ushort(__float2bfloat16(b.y));
        o1.z = __bfloat16_as_ushort(__float2bfloat16(b.z));
        o1.w = __bfloat16_as_ushort(__float2bfloat16(b.w));
        *reinterpret_cast<ushort4*>(xb + i) = o0;
        *reinterpret_cast<ushort4*>(xb + i + 4) = o1;
    } else {
        // wire already bf16: copy 16 B
        *reinterpret_cast<uint4*>(xb + i) =
            *reinterpret_cast<const uint4*>((const unsigned short*)x + i);
    }
}

__global__ void hist_kernel(const int* __restrict__ ei, int* __restrict__ cnt,
                            const int* __restrict__ flags) {
    int i64 = flags[1];
    int e = blockIdx.x * 256 + threadIdx.x;
    int d = i64 ? ei[2 * N_EDGES + 2 * e] : ei[N_EDGES + e];
    atomicAdd(cnt + d, 1);
}

// ---- hierarchical scan ----
__global__ __launch_bounds__(256) void scanA_kernel(const int* __restrict__ cnt,
                                                    int* __restrict__ off,
                                                    int* __restrict__ bsum) {
    __shared__ int tmp[256];
    int t = threadIdx.x;
    int i = blockIdx.x * 256 + t;
    int v = (i < N_NODES) ? cnt[i] : 0;
    tmp[t] = v;
    __syncthreads();
    #pragma unroll
    for (int d = 1; d < 256; d <<= 1) {
        int u = (t >= d) ? tmp[t - d] : 0;
        __syncthreads();
        tmp[t] += u;
        __syncthreads();
    }
    if (i < N_NODES) off[i] = tmp[t] - v;
    if (t == 255) bsum[blockIdx.x] = tmp[255];
}

__global__ __launch_bounds__(256) void scanB_kernel(int* __restrict__ bsum,
                                                    int* __restrict__ off) {
    __shared__ int tmp[256];
    int t = threadIdx.x;
    int v = (t < SCAN_BLOCKS) ? bsum[t] : 0;
    tmp[t] = v;
    __syncthreads();
    #pragma unroll
    for (int d = 1; d < 256; d <<= 1) {
        int u = (t >= d) ? tmp[t - d] : 0;
        __syncthreads();
        tmp[t] += u;
        __syncthreads();
    }
    if (t < SCAN_BLOCKS) bsum[t] = tmp[t] - v;
    if (t == 255) off[N_NODES] = tmp[255];
}

__global__ __launch_bounds__(256) void scanC_kernel(const int* __restrict__ bsum,
                                                    int* __restrict__ off,
                                                    int* __restrict__ cur) {
    int i = blockIdx.x * 256 + threadIdx.x;
    if (i < N_NODES) {
        int o = off[i] + bsum[blockIdx.x];
        off[i] = o;
        cur[i] = o;
    }
}

__global__ void fill_kernel(const int* __restrict__ ei, int* __restrict__ cur,
                            int* __restrict__ srt, const int* __restrict__ flags) {
    int i64 = flags[1];
    int e = blockIdx.x * 256 + threadIdx.x;
    int s, d;
    if (i64) { s = ei[2 * e]; d = ei[2 * N_EDGES + 2 * e]; }
    else     { s = ei[e];     d = ei[N_EDGES + e]; }
    int pos = atomicAdd(cur + d, 1);
    srt[pos] = s;
}

// Fused: CSR bf16-gather (agg = x_i(fp32) + sum bf16(x_j)) -> LDS -> GEMM -> hpre + BN sums.
// 512 threads = 8 waves; each wave gathers 8 rows.
// Lane split for gather: nb = lane>>3 (8 neighbor slots), ch = lane&7 (8 bf16 per 16B load).
__global__ __launch_bounds__(512) void gather_gemm_stats_kernel(
    const unsigned short* __restrict__ xb, const void* __restrict__ self_src, int force_f32,
    const int* __restrict__ off, const int* __restrict__ srt,
    const void* __restrict__ W, const void* __restrict__ bias,
    float* __restrict__ out_, float* __restrict__ sums, const int* __restrict__ flags)
{
    __shared__ float sIn[RPB][DD];            // 16 KB agg tile
    __shared__ float r1[8][DD], r2[8][DD];    // 4 KB stats
    int tid = threadIdx.x;
    int lane = tid & 63, w = tid >> 6;        // wave 0..7
    int nb = lane >> 3, ch = lane & 7;
    int row0 = blockIdx.x * RPB;
    int isf = force_f32 ? 1 : flags[0];

    for (int j = 0; j < 8; ++j) {
        int lr = w * 8 + j;
        int r = row0 + lr;
        float4 a = make_float4(0.f, 0.f, 0.f, 0.f);
        float4 b = make_float4(0.f, 0.f, 0.f, 0.f);
        float4 a2 = make_float4(0.f, 0.f, 0.f, 0.f);
        float4 b2 = make_float4(0.f, 0.f, 0.f, 0.f);
        if (r < N_NODES) {
            int k0 = off[r], k1 = off[r + 1];
            for (int kb = k0; kb < k1; kb += 64) {
                int nload = min(64, k1 - kb);
                int sv = (lane < nload) ? srt[kb + lane] : 0;
                int nfull = nload >> 3;
                int q = 0;
                for (; q + 2 <= nfull; q += 2) {
                    int s0 = __shfl(sv, 8 * q + nb, 64);
                    int s1 = __shfl(sv, 8 * q + 8 + nb, 64);
                    uint4 u0 = *reinterpret_cast<const uint4*>(xb + s0 * DD + 8 * ch);
                    uint4 u1 = *reinterpret_cast<const uint4*>(xb + s1 * DD + 8 * ch);
                    acc8(a, b, u0);
                    acc8(a2, b2, u1);
                }
                if (q < nfull) {
                    int s0 = __shfl(sv, 8 * q + nb, 64);
                    uint4 u0 = *reinterpret_cast<const uint4*>(xb + s0 * DD + 8 * ch);
                    acc8(a, b, u0);
                }
                int rem = nload & 7;
                if (rem) {
                    int s0 = __shfl(sv, 8 * nfull + nb, 64);
                    if (nb < rem) {
                        uint4 u0 = *reinterpret_cast<const uint4*>(xb + s0 * DD + 8 * ch);
                        acc8(a2, b2, u0);
                    }
                }
            }
        }
        a.x += a2.x; a.y += a2.y; a.z += a2.z; a.w += a2.w;
        b.x += b2.x; b.y += b2.y; b.z += b2.z; b.w += b2.w;
        // reduce across nb groups: XOR lanes 8, 16, 32
        #pragma unroll
        for (int d = 8; d < 64; d <<= 1) {
            a.x += __shfl_xor(a.x, d, 64);
            a.y += __shfl_xor(a.y, d, 64);
            a.z += __shfl_xor(a.z, d, 64);
            a.w += __shfl_xor(a.w, d, 64);
            b.x += __shfl_xor(b.x, d, 64);
            b.y += __shfl_xor(b.y, d, 64);
            b.z += __shfl_xor(b.z, d, 64);
            b.w += __shfl_xor(b.w, d, 64);
        }
        if (nb == 0) {
            if (r < N_NODES) {  // fp32 self term
                float4 s0 = isf ? ld4<true>(self_src, r * DD + 8 * ch)
                                : ld4<false>(self_src, r * DD + 8 * ch);
                float4 s1 = isf ? ld4<true>(self_src, r * DD + 8 * ch + 4)
                                : ld4<false>(self_src, r * DD + 8 * ch + 4);
                a.x += s0.x; a.y += s0.y; a.z += s0.z; a.w += s0.w;
                b.x += s1.x; b.y += s1.y; b.z += s1.z; b.w += s1.w;
            }
            *reinterpret_cast<float4*>(&sIn[lr][8 * ch]) = a;
            *reinterpret_cast<float4*>(&sIn[lr][8 * ch + 4]) = b;
        }
    }
    __syncthreads();

    float wcol[DD];                           // W[:,c], c = lane
    #pragma unroll
    for (int k = 0; k < DD; ++k) wcol[k] = loadF(W, k * DD + lane, isf);
    float bv = loadF(bias, lane, isf);

    float s1 = 0.f, s2 = 0.f;
    #pragma unroll 4
    for (int j = 0; j < 8; ++j) {
        int lr = w * 8 + j;
        float a0 = 0.f, a1 = 0.f, a2 = 0.f, a3 = 0.f;
        #pragma unroll
        for (int k = 0; k < DD; k += 4) {
            float4 aa = *reinterpret_cast<const float4*>(&sIn[lr][k]);  // wave-uniform broadcast
            a0 += aa.x * wcol[k];
            a1 += aa.y * wcol[k + 1];
            a2 += aa.z * wcol[k + 2];
            a3 += aa.w * wcol[k + 3];
        }
        float acc = bv + ((a0 + a1) + (a2 + a3));
        int r = row0 + lr;
        if (r < N_NODES) {
            out_[r * DD + lane] = acc;
            s1 += acc;
            s2 += acc * acc;
        }
    }
    r1[w][lane] = s1; r2[w][lane] = s2;
    __syncthreads();
    if (w == 0) {
        float t1 = 0.f, t2 = 0.f;
        #pragma unroll
        for (int q = 0; q < 8; ++q) { t1 += r1[q][lane]; t2 += r2[q][lane]; }
        atomicAdd(&sums[lane], t1);
        atomicAdd(&sums[64 + lane], t2);
    }
}

// sums -> scale/shift (BN affine folded); re-zeroes sums for next layer.
__global__ void bn_params_kernel(float* __restrict__ sums,
                                 const void* __restrict__ gma, const void* __restrict__ beta,
                                 float* __restrict__ scsh, const int* __restrict__ flags) {
    int isf = flags[0];
    int c = threadIdx.x;   // 64 threads
    float S1 = sums[c];
    float S2 = sums[64 + c];
    float mean = S1 * (1.0f / N_NODES);
    float var  = S2 * (1.0f / N_NODES) - mean * mean;
    float scale = rsqrtf(var + BN_EPS) * loadF(gma, c, isf);
    scsh[c] = scale;
    scsh[DD + c] = loadF(beta, c, isf) - mean * scale;
    sums[c] = 0.0f;
    sums[64 + c] = 0.0f;
}

// h = relu(hpre*scale+shift); out = relu(h @ W2 + b2) -> fp32 (+ optional bf16 shadow).
// In-place safe (LDS staged).
__global__ __launch_bounds__(256) void mlp2_kernel(
    const float* __restrict__ in_, const float* __restrict__ scsh,
    const void* __restrict__ W, const void* __restrict__ bias,
    float* __restrict__ oF, unsigned short* obf, const int* __restrict__ flags)
{
    __shared__ float sIn[RPB][DD];
    int isf = flags[0];
    int tid = threadIdx.x;
    int c = tid & 63, g = tid >> 6;
    int row0 = blockIdx.x * RPB;

    #pragma unroll
    for (int j = 0; j < 4; ++j) {
        int lr = (tid >> 4) + 16 * j;
        int cc = (tid & 15) << 2;
        int r = row0 + lr;
        float4 v = make_float4(0.f, 0.f, 0.f, 0.f);
        if (r < N_NODES) {
            v = *reinterpret_cast<const float4*>(in_ + r * DD + cc);
            float4 sc = *reinterpret_cast<const float4*>(scsh + cc);
            float4 sh = *reinterpret_cast<const float4*>(scsh + DD + cc);
            v.x = fmaxf(v.x * sc.x + sh.x, 0.f);
            v.y = fmaxf(v.y * sc.y + sh.y, 0.f);
            v.z = fmaxf(v.z * sc.z + sh.z, 0.f);
            v.w = fmaxf(v.w * sc.w + sh.w, 0.f);
        }
        *reinterpret_cast<float4*>(&sIn[lr][cc]) = v;
    }
    __syncthreads();

    float wcol[DD];
    #pragma unroll
    for (int k = 0; k < DD; ++k) wcol[k] = loadF(W, k * DD + c, isf);
    float bv = loadF(bias, c, isf);

    #pragma unroll 4
    for (int j = 0; j < 16; ++j) {
        int lr = g * 16 + j;
        float a0 = 0.f, a1 = 0.f, a2 = 0.f, a3 = 0.f;
        #pragma unroll
        for (int k = 0; k < DD; k += 4) {
            float4 a = *reinterpret_cast<const float4*>(&sIn[lr][k]);
            a0 += a.x * wcol[k];
            a1 += a.y * wcol[k + 1];
            a2 += a.z * wcol[k + 2];
            a3 += a.w * wcol[k + 3];
        }
        float acc = fmaxf(bv + ((a0 + a1) + (a2 + a3)), 0.f);
        int r = row0 + lr;
        if (r < N_NODES) {
            oF[r * DD + c] = acc;
            if (obf) obf[r * DD + c] = __bfloat16_as_ushort(__float2bfloat16(acc));
        }
    }
}

extern "C" void kernel_launch(void* const* d_in, const int* in_sizes, int n_in,
                              void* d_out, int out_size, void* d_ws, size_t ws_size,
                              hipStream_t stream)
{
    (void)in_sizes; (void)n_in; (void)out_size; (void)ws_size;
    const void* x  = d_in[0];
    const int* ei  = (const int*)d_in[1];
    const void* W1_0 = d_in[2];  const void* b1_0 = d_in[3];
    const void* g_0  = d_in[4];  const void* be_0 = d_in[5];
    const void* W2_0 = d_in[6];  const void* b2_0 = d_in[7];
    const void* W1_1 = d_in[8];  const void* b1_1 = d_in[9];
    const void* g_1  = d_in[10]; const void* be_1 = d_in[11];
    const void* W2_1 = d_in[12]; const void* b2_1 = d_in[13];

    float* wsf  = (float*)d_ws;
    float* sums = wsf;                    // 128
    float* scsh = wsf + 128;              // 128
    int*  flags = (int*)(wsf + 256);      // 2
    int*  cnt   = (int*)(wsf + 512);      // 50000
    int*  off   = cnt + 50048;            // 50001
    int*  cur   = off + 50064;            // 50000
    int*  bsum  = cur + 50048;            // 256
    int*  srt   = bsum + 256;             // 800000
    unsigned short* xb = (unsigned short*)(srt + 800000);  // 3.2M bf16 (6.4 MB)
    float* O1   = (float*)d_out;                  // h1 (fp32 self-term source)
    float* O2   = O1 + (size_t)N_NODES * DD;      // hpre scratch -> h2

    dim3 blk(256);

    // CSR build + bf16 shadow of x
    init_kernel<<<SCAN_BLOCKS, blk, 0, stream>>>(x, ei, flags, cnt, sums);
    cast_kernel<<<(N_NODES * DD / 8 + 255) / 256, blk, 0, stream>>>(x, xb, flags);
    hist_kernel<<<N_EDGES / 256, blk, 0, stream>>>(ei, cnt, flags);
    scanA_kernel<<<SCAN_BLOCKS, blk, 0, stream>>>(cnt, off, bsum);
    scanB_kernel<<<1, blk, 0, stream>>>(bsum, off);
    scanC_kernel<<<SCAN_BLOCKS, blk, 0, stream>>>(bsum, off, cur);
    fill_kernel<<<N_EDGES / 256, blk, 0, stream>>>(ei, cur, srt, flags);

    // ---- layer 1 ----
    gather_gemm_stats_kernel<<<GBLOCKS, 512, 0, stream>>>(xb, x, 0, off, srt, W1_0, b1_0,
                                                          O2, sums, flags);
    bn_params_kernel<<<1, 64, 0, stream>>>(sums, g_0, be_0, scsh, flags);
    // h1 fp32 -> O1, bf16 shadow -> xb (layer-2 gather source)
    mlp2_kernel<<<GBLOCKS, blk, 0, stream>>>(O2, scsh, W2_0, b2_0, O1, xb, flags);

    // ---- layer 2 ----
    gather_gemm_stats_kernel<<<GBLOCKS, 512, 0, stream>>>(xb, O1, 1, off, srt, W1_1, b1_1,
                                                          O2, sums, flags);
    bn_params_kernel<<<1, 64, 0, stream>>>(sums, g_1, be_1, scsh, flags);
    mlp2_kernel<<<GBLOCKS, blk, 0, stream>>>(O2, scsh, W2_1, b2_1, O2, nullptr, flags);
}

// Round 9
// 320.945 us; speedup vs baseline: 1.6815x; 1.0928x over previous
//
#include <hip/hip_runtime.h>
#include <hip/hip_bf16.h>

#define N_NODES 50000
#define N_EDGES 800000
#define DD 64
#define RPB 64
#define GBLOCKS ((N_NODES + RPB - 1) / RPB)       // 782
#define SCAN_BLOCKS ((N_NODES + 255) / 256)       // 196
#define BN_EPS 1e-5f

// ws layout (fp32 words), ~10.2 MB total:
//   [0..127] sums   [128..255] scsh   [256..] flags (isf, i64)
//   [512..]  cnt[50000], off[50001], cur[50000], bsum[256], srt[800000]
//   then xb: 3.2M bf16 (gather shadow: bf16(x) for layer 1, bf16(h1) for layer 2)
// d_out (fp32): O1 = h1 (fp32 self-term source), O2 = hpre scratch -> h2.

__device__ __forceinline__ float bf2f(unsigned short b) {
    return __uint_as_float(((unsigned)b) << 16);
}
__device__ __forceinline__ float loadF(const void* p, int i, int isf) {
    return isf ? ((const float*)p)[i] : bf2f(((const unsigned short*)p)[i]);
}
template<bool ISF>
__device__ __forceinline__ float4 ld4(const void* p, int i) {  // i = elem idx, 4-aligned
    if (ISF) return *reinterpret_cast<const float4*>((const float*)p + i);
    ushort4 u = *reinterpret_cast<const ushort4*>((const unsigned short*)p + i);
    return make_float4(bf2f(u.x), bf2f(u.y), bf2f(u.z), bf2f(u.w));
}
// accumulate 8 bf16 (packed in uint4) into two float4s
__device__ __forceinline__ void acc8(float4& a, float4& b, uint4 u) {
    a.x += __uint_as_float(u.x << 16);
    a.y += __uint_as_float(u.x & 0xFFFF0000u);
    a.z += __uint_as_float(u.y << 16);
    a.w += __uint_as_float(u.y & 0xFFFF0000u);
    b.x += __uint_as_float(u.z << 16);
    b.y += __uint_as_float(u.z & 0xFFFF0000u);
    b.z += __uint_as_float(u.w << 16);
    b.w += __uint_as_float(u.w & 0xFFFF0000u);
}

// zero CSR counts + BN sums; block 0 sniffs wire formats.
__global__ void init_kernel(const void* __restrict__ x, const int* __restrict__ ei,
                            int* __restrict__ flags, int* __restrict__ cnt,
                            float* __restrict__ sums) {
    int i = blockIdx.x * 256 + threadIdx.x;
    if (i < N_NODES) cnt[i] = 0;
    if (i < 128) sums[i] = 0.0f;
    if (blockIdx.x == 0) {
        __shared__ int cntF, cntI;
        int t = threadIdx.x;
        if (t == 0) { cntF = 0; cntI = 0; }
        __syncthreads();
        unsigned short w = ((const unsigned short*)x)[2 * t];
        int e = (w >> 7) & 0xFF;
        if (e >= 0x70 && e <= 0x8F) atomicAdd(&cntF, 1);        // bf16-plausible exponent
        if (t < 128 && ei[2 * t + 1] == 0) atomicAdd(&cntI, 1); // int64 high words are 0
        __syncthreads();
        if (t == 0) {
            flags[0] = (cntF < 128) ? 1 : 0;
            flags[1] = (cntI > 64) ? 1 : 0;
        }
    }
}

// xb[i] = bf16(x[i]), 8 elems/thread
__global__ void cast_kernel(const void* __restrict__ x, unsigned short* __restrict__ xb,
                            const int* __restrict__ flags) {
    int isf = flags[0];
    int i = (blockIdx.x * 256 + threadIdx.x) * 8;
    if (i >= N_NODES * DD) return;
    if (isf) {
        float4 a = *reinterpret_cast<const float4*>((const float*)x + i);
        float4 b = *reinterpret_cast<const float4*>((const float*)x + i + 4);
        ushort4 o0, o1;
        o0.x = __bfloat16_as_ushort(__float2bfloat16(a.x));
        o0.y = __bfloat16_as_ushort(__float2bfloat16(a.y));
        o0.z = __bfloat16_as_ushort(__float2bfloat16(a.z));
        o0.w = __bfloat16_as_ushort(__float2bfloat16(a.w));
        o1.x = __bfloat16_as_ushort(__float2bfloat16(b.x));
        o1.y = __bfloat16_as_ushort(__float2bfloat16(b.y));
        o1.z = __bfloat16_as_ushort(__float2bfloat16(b.z));
        o1.w = __bfloat16_as_ushort(__float2bfloat16(b.w));
        *reinterpret_cast<ushort4*>(xb + i) = o0;
        *reinterpret_cast<ushort4*>(xb + i + 4) = o1;
    } else {
        *reinterpret_cast<uint4*>(xb + i) =
            *reinterpret_cast<const uint4*>((const unsigned short*)x + i);
    }
}

__global__ void hist_kernel(const int* __restrict__ ei, int* __restrict__ cnt,
                            const int* __restrict__ flags) {
    int i64 = flags[1];
    int e = blockIdx.x * 256 + threadIdx.x;
    int d = i64 ? ei[2 * N_EDGES + 2 * e] : ei[N_EDGES + e];
    atomicAdd(cnt + d, 1);
}

// ---- hierarchical scan ----
__global__ __launch_bounds__(256) void scanA_kernel(const int* __restrict__ cnt,
                                                    int* __restrict__ off,
                                                    int* __restrict__ bsum) {
    __shared__ int tmp[256];
    int t = threadIdx.x;
    int i = blockIdx.x * 256 + t;
    int v = (i < N_NODES) ? cnt[i] : 0;
    tmp[t] = v;
    __syncthreads();
    #pragma unroll
    for (int d = 1; d < 256; d <<= 1) {
        int u = (t >= d) ? tmp[t - d] : 0;
        __syncthreads();
        tmp[t] += u;
        __syncthreads();
    }
    if (i < N_NODES) off[i] = tmp[t] - v;
    if (t == 255) bsum[blockIdx.x] = tmp[255];
}

__global__ __launch_bounds__(256) void scanB_kernel(int* __restrict__ bsum,
                                                    int* __restrict__ off) {
    __shared__ int tmp[256];
    int t = threadIdx.x;
    int v = (t < SCAN_BLOCKS) ? bsum[t] : 0;
    tmp[t] = v;
    __syncthreads();
    #pragma unroll
    for (int d = 1; d < 256; d <<= 1) {
        int u = (t >= d) ? tmp[t - d] : 0;
        __syncthreads();
        tmp[t] += u;
        __syncthreads();
    }
    if (t < SCAN_BLOCKS) bsum[t] = tmp[t] - v;
    if (t == 255) off[N_NODES] = tmp[255];
}

__global__ __launch_bounds__(256) void scanC_kernel(const int* __restrict__ bsum,
                                                    int* __restrict__ off,
                                                    int* __restrict__ cur) {
    int i = blockIdx.x * 256 + threadIdx.x;
    if (i < N_NODES) {
        int o = off[i] + bsum[blockIdx.x];
        off[i] = o;
        cur[i] = o;
    }
}

__global__ void fill_kernel(const int* __restrict__ ei, int* __restrict__ cur,
                            int* __restrict__ srt, const int* __restrict__ flags) {
    int i64 = flags[1];
    int e = blockIdx.x * 256 + threadIdx.x;
    int s, d;
    if (i64) { s = ei[2 * e]; d = ei[2 * N_EDGES + 2 * e]; }
    else     { s = ei[e];     d = ei[N_EDGES + e]; }
    int pos = atomicAdd(cur + d, 1);
    srt[pos] = s;
}

// Fused: CSR bf16-gather -> LDS -> GEMM (W1,b1) -> hpre + BN sums.
// 512 threads = 8 waves x 8 row-slots: lane (rs = lane>>3, ch = lane&7) owns the FULL
// neighbor stream of row (w*8 + rs), chunk ch (8 bf16 = 16 B). 8 independent dependency
// chains per wave, no cross-lane reduce, no shfl broadcast (8 lanes share srt[k] addr).
__global__ __launch_bounds__(512) void gather_gemm_stats_kernel(
    const unsigned short* __restrict__ xb, const void* __restrict__ self_src, int force_f32,
    const int* __restrict__ off, const int* __restrict__ srt,
    const void* __restrict__ W, const void* __restrict__ bias,
    float* __restrict__ out_, float* __restrict__ sums, const int* __restrict__ flags)
{
    __shared__ float sIn[RPB][DD];            // 16 KB agg tile
    __shared__ float r1[8][DD], r2[8][DD];    // 4 KB stats
    int tid = threadIdx.x;
    int lane = tid & 63, w = tid >> 6;        // wave 0..7
    int rs = lane >> 3, ch = lane & 7;
    int row0 = blockIdx.x * RPB;
    int isf = force_f32 ? 1 : flags[0];

    int lr = w * 8 + rs;
    int r = row0 + lr;
    float4 a  = make_float4(0.f, 0.f, 0.f, 0.f);
    float4 b  = make_float4(0.f, 0.f, 0.f, 0.f);
    float4 a2 = make_float4(0.f, 0.f, 0.f, 0.f);
    float4 b2 = make_float4(0.f, 0.f, 0.f, 0.f);
    if (r < N_NODES) {
        // fp32/wire self term
        a = isf ? ld4<true>(self_src, r * DD + 8 * ch)
                : ld4<false>(self_src, r * DD + 8 * ch);
        b = isf ? ld4<true>(self_src, r * DD + 8 * ch + 4)
                : ld4<false>(self_src, r * DD + 8 * ch + 4);
        int k0 = off[r], k1 = off[r + 1];
        int k = k0;
        for (; k + 4 <= k1; k += 4) {         // 4-deep pipelined neighbor loads
            int n0 = srt[k], n1 = srt[k + 1], n2 = srt[k + 2], n3 = srt[k + 3];
            uint4 u0 = *reinterpret_cast<const uint4*>(xb + n0 * DD + 8 * ch);
            uint4 u1 = *reinterpret_cast<const uint4*>(xb + n1 * DD + 8 * ch);
            uint4 u2 = *reinterpret_cast<const uint4*>(xb + n2 * DD + 8 * ch);
            uint4 u3 = *reinterpret_cast<const uint4*>(xb + n3 * DD + 8 * ch);
            acc8(a, b, u0);
            acc8(a2, b2, u1);
            acc8(a, b, u2);
            acc8(a2, b2, u3);
        }
        for (; k < k1; ++k) {
            int n0 = srt[k];
            acc8(a, b, *reinterpret_cast<const uint4*>(xb + n0 * DD + 8 * ch));
        }
        a.x += a2.x; a.y += a2.y; a.z += a2.z; a.w += a2.w;
        b.x += b2.x; b.y += b2.y; b.z += b2.z; b.w += b2.w;
    }
    *reinterpret_cast<float4*>(&sIn[lr][8 * ch]) = a;
    *reinterpret_cast<float4*>(&sIn[lr][8 * ch + 4]) = b;
    __syncthreads();

    float wcol[DD];                           // W[:,c], c = lane
    #pragma unroll
    for (int k = 0; k < DD; ++k) wcol[k] = loadF(W, k * DD + lane, isf);
    float bv = loadF(bias, lane, isf);

    float s1 = 0.f, s2 = 0.f;
    #pragma unroll 4
    for (int j = 0; j < 8; ++j) {
        int jr = w * 8 + j;
        float c0 = 0.f, c1 = 0.f, c2 = 0.f, c3 = 0.f;
        #pragma unroll
        for (int k = 0; k < DD; k += 4) {
            float4 aa = *reinterpret_cast<const float4*>(&sIn[jr][k]);  // wave-uniform broadcast
            c0 += aa.x * wcol[k];
            c1 += aa.y * wcol[k + 1];
            c2 += aa.z * wcol[k + 2];
            c3 += aa.w * wcol[k + 3];
        }
        float acc = bv + ((c0 + c1) + (c2 + c3));
        int rr = row0 + jr;
        if (rr < N_NODES) {
            out_[rr * DD + lane] = acc;
            s1 += acc;
            s2 += acc * acc;
        }
    }
    r1[w][lane] = s1; r2[w][lane] = s2;
    __syncthreads();
    if (w == 0) {
        float t1 = 0.f, t2 = 0.f;
        #pragma unroll
        for (int q = 0; q < 8; ++q) { t1 += r1[q][lane]; t2 += r2[q][lane]; }
        atomicAdd(&sums[lane], t1);
        atomicAdd(&sums[64 + lane], t2);
    }
}

// sums -> scale/shift (BN affine folded); re-zeroes sums for next layer.
__global__ void bn_params_kernel(float* __restrict__ sums,
                                 const void* __restrict__ gma, const void* __restrict__ beta,
                                 float* __restrict__ scsh, const int* __restrict__ flags) {
    int isf = flags[0];
    int c = threadIdx.x;   // 64 threads
    float S1 = sums[c];
    float S2 = sums[64 + c];
    float mean = S1 * (1.0f / N_NODES);
    float var  = S2 * (1.0f / N_NODES) - mean * mean;
    float scale = rsqrtf(var + BN_EPS) * loadF(gma, c, isf);
    scsh[c] = scale;
    scsh[DD + c] = loadF(beta, c, isf) - mean * scale;
    sums[c] = 0.0f;
    sums[64 + c] = 0.0f;
}

// h = relu(hpre*scale+shift); out = relu(h @ W2 + b2) -> fp32 (+ optional bf16 shadow).
// In-place safe (LDS staged).
__global__ __launch_bounds__(256) void mlp2_kernel(
    const float* __restrict__ in_, const float* __restrict__ scsh,
    const void* __restrict__ W, const void* __restrict__ bias,
    float* __restrict__ oF, unsigned short* obf, const int* __restrict__ flags)
{
    __shared__ float sIn[RPB][DD];
    int isf = flags[0];
    int tid = threadIdx.x;
    int c = tid & 63, g = tid >> 6;
    int row0 = blockIdx.x * RPB;

    #pragma unroll
    for (int j = 0; j < 4; ++j) {
        int lr = (tid >> 4) + 16 * j;
        int cc = (tid & 15) << 2;
        int r = row0 + lr;
        float4 v = make_float4(0.f, 0.f, 0.f, 0.f);
        if (r < N_NODES) {
            v = *reinterpret_cast<const float4*>(in_ + r * DD + cc);
            float4 sc = *reinterpret_cast<const float4*>(scsh + cc);
            float4 sh = *reinterpret_cast<const float4*>(scsh + DD + cc);
            v.x = fmaxf(v.x * sc.x + sh.x, 0.f);
            v.y = fmaxf(v.y * sc.y + sh.y, 0.f);
            v.z = fmaxf(v.z * sc.z + sh.z, 0.f);
            v.w = fmaxf(v.w * sc.w + sh.w, 0.f);
        }
        *reinterpret_cast<float4*>(&sIn[lr][cc]) = v;
    }
    __syncthreads();

    float wcol[DD];
    #pragma unroll
    for (int k = 0; k < DD; ++k) wcol[k] = loadF(W, k * DD + c, isf);
    float bv = loadF(bias, c, isf);

    #pragma unroll 4
    for (int j = 0; j < 16; ++j) {
        int lr = g * 16 + j;
        float a0 = 0.f, a1 = 0.f, a2 = 0.f, a3 = 0.f;
        #pragma unroll
        for (int k = 0; k < DD; k += 4) {
            float4 a = *reinterpret_cast<const float4*>(&sIn[lr][k]);
            a0 += a.x * wcol[k];
            a1 += a.y * wcol[k + 1];
            a2 += a.z * wcol[k + 2];
            a3 += a.w * wcol[k + 3];
        }
        float acc = fmaxf(bv + ((a0 + a1) + (a2 + a3)), 0.f);
        int r = row0 + lr;
        if (r < N_NODES) {
            oF[r * DD + c] = acc;
            if (obf) obf[r * DD + c] = __bfloat16_as_ushort(__float2bfloat16(acc));
        }
    }
}

extern "C" void kernel_launch(void* const* d_in, const int* in_sizes, int n_in,
                              void* d_out, int out_size, void* d_ws, size_t ws_size,
                              hipStream_t stream)
{
    (void)in_sizes; (void)n_in; (void)out_size; (void)ws_size;
    const void* x  = d_in[0];
    const int* ei  = (const int*)d_in[1];
    const void* W1_0 = d_in[2];  const void* b1_0 = d_in[3];
    const void* g_0  = d_in[4];  const void* be_0 = d_in[5];
    const void* W2_0 = d_in[6];  const void* b2_0 = d_in[7];
    const void* W1_1 = d_in[8];  const void* b1_1 = d_in[9];
    const void* g_1  = d_in[10]; const void* be_1 = d_in[11];
    const void* W2_1 = d_in[12]; const void* b2_1 = d_in[13];

    float* wsf  = (float*)d_ws;
    float* sums = wsf;                    // 128
    float* scsh = wsf + 128;              // 128
    int*  flags = (int*)(wsf + 256);      // 2
    int*  cnt   = (int*)(wsf + 512);      // 50000
    int*  off   = cnt + 50048;            // 50001
    int*  cur   = off + 50064;            // 50000
    int*  bsum  = cur + 50048;            // 256
    int*  srt   = bsum + 256;             // 800000
    unsigned short* xb = (unsigned short*)(srt + 800000);  // 3.2M bf16 (6.4 MB), 16B-aligned
    float* O1   = (float*)d_out;                  // h1 (fp32 self-term source)
    float* O2   = O1 + (size_t)N_NODES * DD;      // hpre scratch -> h2

    dim3 blk(256);

    // CSR build + bf16 shadow of x
    init_kernel<<<SCAN_BLOCKS, blk, 0, stream>>>(x, ei, flags, cnt, sums);
    cast_kernel<<<(N_NODES * DD / 8 + 255) / 256, blk, 0, stream>>>(x, xb, flags);
    hist_kernel<<<N_EDGES / 256, blk, 0, stream>>>(ei, cnt, flags);
    scanA_kernel<<<SCAN_BLOCKS, blk, 0, stream>>>(cnt, off, bsum);
    scanB_kernel<<<1, blk, 0, stream>>>(bsum, off);
    scanC_kernel<<<SCAN_BLOCKS, blk, 0, stream>>>(bsum, off, cur);
    fill_kernel<<<N_EDGES / 256, blk, 0, stream>>>(ei, cur, srt, flags);

    // ---- layer 1 ----
    gather_gemm_stats_kernel<<<GBLOCKS, 512, 0, stream>>>(xb, x, 0, off, srt, W1_0, b1_0,
                                                          O2, sums, flags);
    bn_params_kernel<<<1, 64, 0, stream>>>(sums, g_0, be_0, scsh, flags);
    // h1 fp32 -> O1, bf16 shadow -> xb (layer-2 gather source)
    mlp2_kernel<<<GBLOCKS, blk, 0, stream>>>(O2, scsh, W2_0, b2_0, O1, xb, flags);

    // ---- layer 2 ----
    gather_gemm_stats_kernel<<<GBLOCKS, 512, 0, stream>>>(xb, O1, 1, off, srt, W1_1, b1_1,
                                                          O2, sums, flags);
    bn_params_kernel<<<1, 64, 0, stream>>>(sums, g_1, be_1, scsh, flags);
    mlp2_kernel<<<GBLOCKS, blk, 0, stream>>>(O2, scsh, W2_1, b2_1, O2, nullptr, flags);
}